// Round 15
// baseline (156.484 us; speedup 1.0000x reference)
//
#include <hip/hip_runtime.h>
#include <hip/hip_bf16.h>
#include <stdint.h>

typedef float f32x4 __attribute__((ext_vector_type(4)));
typedef short bf16x8 __attribute__((ext_vector_type(8)));
typedef _Float16 f16x8 __attribute__((ext_vector_type(8)));

#define DEV static __device__ __forceinline__

DEV float bf2f(short u) {
  union { float f; unsigned i; } v;
  v.i = ((unsigned)(unsigned short)u) << 16;
  return v.f;
}
DEV short f2bf(float f) {
  union { float f; unsigned i; } v;
  v.f = f;
  unsigned lsb = (v.i >> 16) & 1u;
  v.i += 0x7fffu + lsb;
  return (short)(v.i >> 16);
}
DEV short f2h(float f) {
  union { _Float16 h; short s; } u;
  u.h = (_Float16)f;
  return u.s;
}

DEV void glds16(const void* g, void* l) {
  __builtin_amdgcn_global_load_lds(
      (const __attribute__((address_space(1))) void*)g,
      (__attribute__((address_space(3))) void*)l, 16, 0, 0);
}

// ---------------------------------------------------------------------------
// Convert fp32 -> fp16 (x, y, Wq, Wk, Wv) and bf16 (Wo)
// ---------------------------------------------------------------------------
__global__ __launch_bounds__(256) void k_convert(
    const float* __restrict__ x, const float* __restrict__ y,
    const float* __restrict__ wq, const float* __restrict__ wk,
    const float* __restrict__ wv, const float* __restrict__ wo,
    short* __restrict__ x16, short* __restrict__ y16,
    short* __restrict__ wq16, short* __restrict__ wk16,
    short* __restrict__ wv16, short* __restrict__ wohi) {
  const float* src; short* dst; int n, half;
  switch (blockIdx.y) {
    case 0: src = x;  dst = x16;  n = 4194304; half = 1; break;
    case 1: src = y;  dst = y16;  n = 4194304; half = 1; break;
    case 2: src = wq; dst = wq16; n = 1048576; half = 1; break;
    case 3: src = wk; dst = wk16; n = 1048576; half = 1; break;
    case 4: src = wv; dst = wv16; n = 1048576; half = 1; break;
    default: src = wo; dst = wohi; n = 1048576; half = 0; break;
  }
  int i4 = blockIdx.x * 256 + threadIdx.x;
  if (i4 * 4 >= n) return;
  float4 v = ((const float4*)src)[i4];
  short4 h;
  float* pv = (float*)&v;
  short* ph = (short*)&h;
#pragma unroll
  for (int e = 0; e < 4; ++e) ph[e] = half ? f2h(pv[e]) : f2bf(pv[e]);
  ((short4*)dst)[i4] = h;
}

// ---------------------------------------------------------------------------
// XCD-pinned block remap for 128x64 tiles: M=4096(32 row-panels) x
// N=1024(16 col-blocks). wg = rhigh*128 + c*8 + rlow (bijective, 512 blocks).
// ---------------------------------------------------------------------------
DEV void gemm_block_map64(int wg, long& bRow, long& bCol) {
  int rlow = wg & 7, c = (wg >> 3) & 15, rhigh = wg >> 7;
  bRow = (long)(rhigh * 8 + rlow) * 128;
  bCol = (long)c * 64;
}

// ---------------------------------------------------------------------------
// Plain bf16 NT GEMM with bias (Wo output projection). 128x64 tile,
// 4 waves (256 thr), double-buffered, 512 blocks = 2 blocks/CU.
// ---------------------------------------------------------------------------
__global__ __launch_bounds__(256) void k_gemm_out(
    const short* __restrict__ A, const short* __restrict__ B,
    const float* __restrict__ bias, float* __restrict__ C, int M, int N, int K) {
  __shared__ __align__(16) short As[2][128 * 64];
  __shared__ __align__(16) short Bs[2][64 * 64];
  const int tid = threadIdx.x, lane = tid & 63;
  const int w = tid >> 6;
  const int lo = lane & 15, hi4 = lane >> 4;
  long bRow, bCol;
  gemm_block_map64(blockIdx.x, bRow, bCol);
  f32x4 acc[2][4] = {};
  const int nks = K >> 6;
  auto stage = [&](int buf, int ks) {
#pragma unroll
    for (int i = 0; i < 4; ++i) {
      int c = i * 256 + tid;
      int r = c >> 3;
      int wi = ((c & 7) * 16) ^ ((r & 7) << 4);
      glds16((const char*)A + (bRow + r) * (long)(K * 2) + ks * 128 + wi, (char*)As[buf] + c * 16);
    }
#pragma unroll
    for (int i = 0; i < 2; ++i) {
      int c = i * 256 + tid;
      int r = c >> 3;
      int wi = ((c & 7) * 16) ^ ((r & 7) << 4);
      glds16((const char*)B + (bCol + r) * (long)(K * 2) + ks * 128 + wi, (char*)Bs[buf] + c * 16);
    }
  };
  stage(0, 0);
  __syncthreads();
  int p = 0;
  for (int ks = 0; ks < nks; ++ks) {
    if (ks + 1 < nks) stage(p ^ 1, ks + 1);
#pragma unroll
    for (int kk = 0; kk < 2; ++kk) {
      bf16x8 af[2], bfr[4];
#pragma unroll
      for (int m = 0; m < 2; ++m) {
        int r = w * 32 + m * 16 + lo;
        af[m] = *(const bf16x8*)((const char*)As[p] + r * 128 + ((kk * 64 + hi4 * 16) ^ ((r & 7) << 4)));
      }
#pragma unroll
      for (int n = 0; n < 4; ++n) {
        int r = n * 16 + lo;
        bfr[n] = *(const bf16x8*)((const char*)Bs[p] + r * 128 + ((kk * 64 + hi4 * 16) ^ ((r & 7) << 4)));
      }
#pragma unroll
      for (int m = 0; m < 2; ++m)
#pragma unroll
        for (int n = 0; n < 4; ++n)
          acc[m][n] = __builtin_amdgcn_mfma_f32_16x16x32_bf16(af[m], bfr[n], acc[m][n], 0, 0, 0);
    }
    __syncthreads();
    p ^= 1;
  }
#pragma unroll
  for (int n = 0; n < 4; ++n) {
    long col = bCol + n * 16 + lo;
    float bv = bias[col];
#pragma unroll
    for (int m = 0; m < 2; ++m) {
      long row0 = bRow + w * 32 + m * 16 + hi4 * 4;
#pragma unroll
      for (int j = 0; j < 4; ++j)
        C[(row0 + j) * N + col] = acc[m][n][j] + bv;
    }
  }
}

// ---------------------------------------------------------------------------
// fp16 NT GEMM with bias, 128x64 tile, 4 waves, double-buffered, 512 blocks.
// OUT_MODE=2: fp16 out. 0: bf16 out.
// ---------------------------------------------------------------------------
template <int OUT_MODE>
__global__ __launch_bounds__(256) void k_gemm_f16(
    const short* __restrict__ A, const short* __restrict__ B,
    const float* __restrict__ bias, short* __restrict__ C, int M, int N, int K) {
  __shared__ __align__(16) short As[2][128 * 64];
  __shared__ __align__(16) short Bs[2][64 * 64];
  const int tid = threadIdx.x, lane = tid & 63;
  const int w = tid >> 6;
  const int lo = lane & 15, hi4 = lane >> 4;
  long bRow, bCol;
  gemm_block_map64(blockIdx.x, bRow, bCol);
  f32x4 acc[2][4] = {};
  const int nks = K >> 6;
  auto stage = [&](int buf, int ks) {
#pragma unroll
    for (int i = 0; i < 4; ++i) {
      int c = i * 256 + tid;
      int r = c >> 3;
      int wi = ((c & 7) * 16) ^ ((r & 7) << 4);
      glds16((const char*)A + (bRow + r) * (long)(K * 2) + ks * 128 + wi, (char*)As[buf] + c * 16);
    }
#pragma unroll
    for (int i = 0; i < 2; ++i) {
      int c = i * 256 + tid;
      int r = c >> 3;
      int wi = ((c & 7) * 16) ^ ((r & 7) << 4);
      glds16((const char*)B + (bCol + r) * (long)(K * 2) + ks * 128 + wi, (char*)Bs[buf] + c * 16);
    }
  };
  stage(0, 0);
  __syncthreads();
  int p = 0;
  for (int ks = 0; ks < nks; ++ks) {
    if (ks + 1 < nks) stage(p ^ 1, ks + 1);
#pragma unroll
    for (int kk = 0; kk < 2; ++kk) {
      f16x8 af[2], bfr[4];
#pragma unroll
      for (int m = 0; m < 2; ++m) {
        int r = w * 32 + m * 16 + lo;
        af[m] = *(const f16x8*)((const char*)As[p] + r * 128 + ((kk * 64 + hi4 * 16) ^ ((r & 7) << 4)));
      }
#pragma unroll
      for (int n = 0; n < 4; ++n) {
        int r = n * 16 + lo;
        bfr[n] = *(const f16x8*)((const char*)Bs[p] + r * 128 + ((kk * 64 + hi4 * 16) ^ ((r & 7) << 4)));
      }
#pragma unroll
      for (int m = 0; m < 2; ++m)
#pragma unroll
        for (int n = 0; n < 4; ++n)
          acc[m][n] = __builtin_amdgcn_mfma_f32_16x16x32_f16(af[m], bfr[n], acc[m][n], 0, 0, 0);
    }
    __syncthreads();
    p ^= 1;
  }
#pragma unroll
  for (int n = 0; n < 4; ++n) {
    long col = bCol + n * 16 + lo;
    float bv = bias[col];
#pragma unroll
    for (int m = 0; m < 2; ++m)
#pragma unroll
      for (int j = 0; j < 4; ++j) {
        long row = bRow + w * 32 + m * 16 + hi4 * 4 + j;
        float v = acc[m][n][j] + bv;
        C[row * N + col] = (OUT_MODE == 2) ? f2h(v) : f2bf(v);
      }
  }
}

// ---------------------------------------------------------------------------
// k_mu: Thr[g,s] = (q_s . sum_t k_t) * NORM / 1024.  4 blocks per slice.
// ---------------------------------------------------------------------------
__global__ __launch_bounds__(256) void k_mu(
    const short* __restrict__ K16, const short* __restrict__ Q16,
    float* __restrict__ Thr) {
  __shared__ float tmp[32][64];
  __shared__ float ksum[64];
  const int g = blockIdx.x >> 2, q = blockIdx.x & 3;
  const int tid = threadIdx.x;
  const int d8 = tid & 7, tq = tid >> 3;
  const short* kp = K16 + (long)g * 65536;
  float acc[8] = {};
  for (int t = tq; t < 1024; t += 32) {
    f16x8 a = *(const f16x8*)(kp + t * 64 + d8 * 8);
#pragma unroll
    for (int e = 0; e < 8; ++e) acc[e] += (float)a[e];
  }
#pragma unroll
  for (int e = 0; e < 8; ++e) tmp[tq][d8 * 8 + e] = acc[e];
  __syncthreads();
  if (tid < 64) {
    float s = 0.f;
#pragma unroll
    for (int qq = 0; qq < 32; ++qq) s += tmp[qq][tid];
    ksum[tid] = s;
  }
  __syncthreads();
  const float c = 0.03125f / 1024.f;
  const int s = q * 256 + tid;
  const short* qp = Q16 + (long)g * 65536 + s * 64;
  float dot = 0.f;
#pragma unroll
  for (int d0 = 0; d0 < 64; d0 += 8) {
    f16x8 a = *(const f16x8*)(qp + d0);
#pragma unroll
    for (int e = 0; e < 8; ++e) dot += (float)a[e] * ksum[d0 + e];
  }
  Thr[g * 1024 + s] = dot * c;
}

// ---------------------------------------------------------------------------
// Pass A FUSED with V-scale/transpose (unchanged from round 14).
// ---------------------------------------------------------------------------
__global__ __launch_bounds__(256) void k_passA_fuse(
    const short* __restrict__ Q16, const short* __restrict__ K16,
    const short* __restrict__ Vb, short* __restrict__ Vt,
    short* __restrict__ rlbf) {
  __shared__ __align__(16) short Ks[64 * 64];
  __shared__ __align__(16) short Qs[2][64 * 64];
  __shared__ __align__(16) short T[64][80];
  __shared__ float rls[64];
  const int wg = blockIdx.x;
  const int g = (wg & 7) | ((wg >> 7) << 3);
  const int tb = (wg >> 3) & 15;
  const int tid = threadIdx.x, lane = tid & 63;
  const int w = tid >> 6;
  const int lo = lane & 15, hi4 = lane >> 4;
  const long gbase = (long)g * 131072;
  const float CEXP = 0.045136860026163146f;  // 2^-5 * log2(e)

  const short* vsrc = Vb + (long)g * 65536 + (long)tb * 64 * 64;
  bf16x8 vreg[2];
#pragma unroll
  for (int i = 0; i < 2; ++i) {
    int c = i * 256 + tid;
    vreg[i] = *(const bf16x8*)(vsrc + (c >> 3) * 64 + (c & 7) * 8);
  }

  auto stageQ = [&](int buf, int sb) {
#pragma unroll
    for (int i = 0; i < 2; ++i) {
      int c = i * 256 + tid;
      int r = c >> 3;
      int wi = ((c & 7) * 16) ^ ((r & 7) << 4);
      glds16((const char*)Q16 + gbase + (long)(sb * 64 + r) * 128 + wi, (char*)Qs[buf] + c * 16);
    }
  };
#pragma unroll
  for (int i = 0; i < 2; ++i) {
    int c = i * 256 + tid;
    int r = c >> 3;
    int wi = ((c & 7) * 16) ^ ((r & 7) << 4);
    glds16((const char*)K16 + gbase + (long)(tb * 64 + r) * 128 + wi, (char*)Ks + c * 16);
  }
  stageQ(0, 0);
  __syncthreads();
  f16x8 kf[2];
#pragma unroll
  for (int kk = 0; kk < 2; ++kk) {
    int r = w * 16 + lo;
    kf[kk] = *(const f16x8*)((const char*)Ks + r * 128 + ((kk * 64 + hi4 * 16) ^ ((r & 7) << 4)));
  }
  float Lacc[4] = {};
  int p = 0;
  for (int sb = 0; sb < 16; ++sb) {
    if (sb < 15) stageQ(p ^ 1, sb + 1);
    f32x4 s[4] = {};
#pragma unroll
    for (int kk = 0; kk < 2; ++kk) {
#pragma unroll
      for (int n = 0; n < 4; ++n) {
        int r = n * 16 + lo;
        f16x8 qf = *(const f16x8*)((const char*)Qs[p] + r * 128 +
                                   ((kk * 64 + hi4 * 16) ^ ((r & 7) << 4)));
        __builtin_amdgcn_s_setprio(1);
        s[n] = __builtin_amdgcn_mfma_f32_16x16x32_f16(kf[kk], qf, s[n], 0, 0, 0);
        __builtin_amdgcn_s_setprio(0);
      }
    }
#pragma unroll
    for (int n = 0; n < 4; ++n)
#pragma unroll
      for (int j = 0; j < 4; ++j)
        Lacc[j] += __builtin_amdgcn_exp2f(s[n][j] * CEXP);
    __syncthreads();
    p ^= 1;
  }
#pragma unroll
  for (int j = 0; j < 4; ++j) {
    float v = Lacc[j];
    v += __shfl_xor(v, 1);
    v += __shfl_xor(v, 2);
    v += __shfl_xor(v, 4);
    v += __shfl_xor(v, 8);
    if (lo == 0) {
      float rv = 1.0f / v;
      int idx = w * 16 + hi4 * 4 + j;
      rls[idx] = rv;
      rlbf[g * 1024 + tb * 64 + idx] = f2bf(rv);
    }
  }
  __syncthreads();
#pragma unroll
  for (int i = 0; i < 2; ++i) {
    int c = i * 256 + tid;
    int t = c >> 3, dc = (c & 7) * 8;
    float rv = rls[t];
#pragma unroll
    for (int e = 0; e < 8; ++e) T[dc + e][t] = f2bf(bf2f(vreg[i][e]) * rv);
  }
  __syncthreads();
  short* dst = Vt + (long)g * 65536 + tb * 64;
#pragma unroll
  for (int i = 0; i < 2; ++i) {
    int c = i * 256 + tid;
    int d = c >> 3, tc = (c & 7) * 8;
    bf16x8 o = *(const bf16x8*)(&T[d][tc]);
    *(bf16x8*)(dst + (long)d * 1024 + tc) = o;
  }
}

// ---------------------------------------------------------------------------
// Pass B (LDS-amortized): block owns 128 s-rows (grid 512, 2 blocks/CU);
// each wave owns 32 s-rows as two 16-row groups u=0,1. The 8 K-reads and
// 8 V-reads per wave-tile are SHARED across both groups (2x reuse), cutting
// per-unit LDS-pipe traffic 296 -> 200 cyc. Numerics identical to round 14.
// LDS = 32KB K/V dbuf + 16KB P = 48KB.
// ---------------------------------------------------------------------------
__global__ __launch_bounds__(256, 2) void k_passB(
    const short* __restrict__ Q16, const short* __restrict__ K16,
    const short* __restrict__ Vt, const short* __restrict__ rlbf,
    const float* __restrict__ Thr, short* __restrict__ Pre,
    const int* __restrict__ rmask) {
  __shared__ __align__(16) short Ks[2][64 * 64];
  __shared__ __align__(16) short Vs[2][64 * 64];
  __shared__ __align__(16) short Ps[128 * 64];
  const int wg = blockIdx.x;
  const int g = (wg & 7) | ((wg >> 6) << 3);  // slice pinned to XCD g&7
  const int rb = (wg >> 3) & 7;               // 8 row-blocks of 128
  const int tid = threadIdx.x, lane = tid & 63;
  const int w = tid >> 6;
  const int lo = lane & 15, hi4 = lane >> 4;
  const long gbase = (long)g * 131072;
  const bool use_mask = (*rmask != 0);
  const float CEXP = 0.045136860026163146f;  // 2^-5 * log2(e)

  auto stage = [&](int buf, int tb2) {
#pragma unroll
    for (int i = 0; i < 2; ++i) {
      int c = i * 256 + tid;
      int r = c >> 3;
      int wi = ((c & 7) * 16) ^ ((r & 7) << 4);
      glds16((const char*)K16 + gbase + (long)(tb2 * 64 + r) * 128 + wi, (char*)Ks[buf] + c * 16);
      glds16((const char*)Vt + gbase + (long)r * 2048 + tb2 * 128 + wi, (char*)Vs[buf] + c * 16);
    }
  };

  // per-group Q fragments + thresholds (group u covers s-rows w*32+u*16+lo)
  f16x8 qf[2][2];
  float thre32[2];
#pragma unroll
  for (int u = 0; u < 2; ++u) {
    int srow = w * 32 + u * 16 + lo;
    const char* qr = (const char*)Q16 + gbase + (long)(rb * 128 + srow) * 128;
#pragma unroll
    for (int kk = 0; kk < 2; ++kk)
      qf[u][kk] = *(const f16x8*)(qr + kk * 64 + hi4 * 16);
    thre32[u] = use_mask ? Thr[g * 1024 + rb * 128 + srow] * 32.0f : -3.4e38f;
  }

  f32x4 o1[2][4] = {}, o2[2][4] = {};
  f32x4 o1R[2] = {}, o2Z[2] = {};

  stage(0, 0);
  __syncthreads();
  int p = 0;
  for (int tb = 0; tb < 16; ++tb) {
    if (tb < 15) stage(p ^ 1, tb + 1);
    // --- S^T for BOTH groups, sharing the K-fragment reads (8 b128) ---
    f32x4 s0[4] = {}, s1[4] = {};
#pragma unroll
    for (int kk = 0; kk < 2; ++kk) {
#pragma unroll
      for (int n = 0; n < 4; ++n) {
        int r = n * 16 + lo;
        f16x8 kf = *(const f16x8*)((const char*)Ks[p] + r * 128 +
                                   ((kk * 64 + hi4 * 16) ^ ((r & 7) << 4)));
        __builtin_amdgcn_s_setprio(1);
        s0[n] = __builtin_amdgcn_mfma_f32_16x16x32_f16(kf, qf[0][kk], s0[n], 0, 0, 0);
        s1[n] = __builtin_amdgcn_mfma_f32_16x16x32_f16(kf, qf[1][kk], s1[n], 0, 0, 0);
        __builtin_amdgcn_s_setprio(0);
      }
    }
    // --- softmax both groups: P1 = e stored, P2 words kept in regs ---
    unsigned p2w0[2][4], p2w1[2][4];
#pragma unroll
    for (int u = 0; u < 2; ++u) {
      int prow = w * 32 + u * 16 + lo;
#pragma unroll
      for (int n = 0; n < 4; ++n) {
        f32x4 sv = u ? s1[n] : s0[n];
        float ev[4], p2v[4];
#pragma unroll
        for (int j = 0; j < 4; ++j) {
          float sraw = sv[j];
          float e = __builtin_amdgcn_exp2f(sraw * CEXP);
          ev[j] = e;
          p2v[j] = (sraw > thre32[u]) ? e : 0.f;
        }
        unsigned u10, u11, u20, u21;
        asm("v_cvt_pk_bf16_f32 %0, %1, %2" : "=v"(u10) : "v"(ev[0]), "v"(ev[1]));
        asm("v_cvt_pk_bf16_f32 %0, %1, %2" : "=v"(u11) : "v"(ev[2]), "v"(ev[3]));
        asm("v_cvt_pk_bf16_f32 %0, %1, %2" : "=v"(u20) : "v"(p2v[0]), "v"(p2v[1]));
        asm("v_cvt_pk_bf16_f32 %0, %1, %2" : "=v"(u21) : "v"(p2v[2]), "v"(p2v[3]));
        p2w0[u][n] = u20;
        p2w1[u][n] = u21;
        int colb = n * 32 + hi4 * 8;
        int boff = prow * 128 + (colb ^ ((prow & 7) << 4));
        uint2 w1; w1.x = u10; w1.y = u11;
        *(uint2*)((char*)Ps + boff) = w1;
      }
    }
    // --- PV pass 1 (both groups share the 8 V-fragment reads) ---
    bf16x8 vbreg[2][4], rlfr[2];
#pragma unroll
    for (int kk = 0; kk < 2; ++kk) {
      rlfr[kk] = *(const bf16x8*)(rlbf + g * 1024 + tb * 64 + kk * 32 + hi4 * 8);
#pragma unroll
      for (int n = 0; n < 4; ++n) {
        int d = n * 16 + lo;
        vbreg[kk][n] = *(const bf16x8*)((const char*)Vs[p] + d * 128 +
                                        ((kk * 64 + hi4 * 16) ^ ((d & 7) << 4)));
      }
#pragma unroll
      for (int u = 0; u < 2; ++u) {
        int prow = w * 32 + u * 16 + lo;
        int poff = prow * 128 + ((kk * 64 + hi4 * 16) ^ ((prow & 7) << 4));
        bf16x8 pa1 = *(const bf16x8*)((const char*)Ps + poff);
        __builtin_amdgcn_s_setprio(1);
        o1R[u] = __builtin_amdgcn_mfma_f32_16x16x32_bf16(pa1, rlfr[kk], o1R[u], 0, 0, 0);
#pragma unroll
        for (int n = 0; n < 4; ++n)
          o1[u][n] = __builtin_amdgcn_mfma_f32_16x16x32_bf16(pa1, vbreg[kk][n], o1[u][n], 0, 0, 0);
        __builtin_amdgcn_s_setprio(0);
      }
    }
    // --- store P2 over same buffer (wave-exclusive rows) ---
#pragma unroll
    for (int u = 0; u < 2; ++u) {
      int prow = w * 32 + u * 16 + lo;
#pragma unroll
      for (int n = 0; n < 4; ++n) {
        int colb = n * 32 + hi4 * 8;
        int boff = prow * 128 + (colb ^ ((prow & 7) << 4));
        uint2 w2; w2.x = p2w0[u][n]; w2.y = p2w1[u][n];
        *(uint2*)((char*)Ps + boff) = w2;
      }
    }
    // --- PV pass 2 ---
#pragma unroll
    for (int kk = 0; kk < 2; ++kk) {
#pragma unroll
      for (int u = 0; u < 2; ++u) {
        int prow = w * 32 + u * 16 + lo;
        int poff = prow * 128 + ((kk * 64 + hi4 * 16) ^ ((prow & 7) << 4));
        bf16x8 pa2 = *(const bf16x8*)((const char*)Ps + poff);
        __builtin_amdgcn_s_setprio(1);
        o2Z[u] = __builtin_amdgcn_mfma_f32_16x16x32_bf16(pa2, rlfr[kk], o2Z[u], 0, 0, 0);
#pragma unroll
        for (int n = 0; n < 4; ++n)
          o2[u][n] = __builtin_amdgcn_mfma_f32_16x16x32_bf16(pa2, vbreg[kk][n], o2[u][n], 0, 0, 0);
        __builtin_amdgcn_s_setprio(0);
      }
    }
    __syncthreads();
    p ^= 1;
  }
  // --- epilogue ---
#pragma unroll
  for (int u = 0; u < 2; ++u)
#pragma unroll
    for (int j = 0; j < 4; ++j) {
      float rr = fmaxf(o1R[u][j], 1e-12f);
      float zz = fmaxf(o2Z[u][j], 1e-30f);
      float rinv = 0.5f / rr;
      float zinv = 0.5f / zz;
      int row = rb * 128 + w * 32 + u * 16 + hi4 * 4 + j;
#pragma unroll
      for (int n = 0; n < 4; ++n) {
        float val = o1[u][n][j] * rinv + o2[u][n][j] * zinv;
        Pre[(long)g * 65536 + (long)row * 64 + n * 16 + lo] = f2bf(val);
      }
    }
}

// ---------------------------------------------------------------------------
extern "C" void kernel_launch(void* const* d_in, const int* in_sizes, int n_in,
                              void* d_out, int out_size, void* d_ws, size_t ws_size,
                              hipStream_t stream) {
  const float* x  = (const float*)d_in[0];
  const float* y  = (const float*)d_in[1];
  const float* Wq = (const float*)d_in[2];
  const float* bq = (const float*)d_in[3];
  const float* Wk = (const float*)d_in[4];
  const float* bk = (const float*)d_in[5];
  const float* Wv = (const float*)d_in[6];
  const float* bv = (const float*)d_in[7];
  const float* Wo = (const float*)d_in[8];
  const float* bo = (const float*)d_in[9];
  const int* rm   = (const int*)d_in[10];
  float* out = (float*)d_out;

  char* ws = (char*)d_ws;
  size_t off = 0;
  auto alloc = [&](size_t bytes) {
    char* p = ws + off;
    off += (bytes + 255) & ~(size_t)255;
    return p;
  };
  short* x16  = (short*)alloc(4194304 * 2);
  short* y16  = (short*)alloc(4194304 * 2);
  short* wq16 = (short*)alloc(1048576 * 2);
  short* wk16 = (short*)alloc(1048576 * 2);
  short* wv16 = (short*)alloc(1048576 * 2);
  short* wohi = (short*)alloc(1048576 * 2);
  short* Q16  = (short*)alloc(4194304 * 2);
  short* K16  = (short*)alloc(4194304 * 2);
  short* Vb   = (short*)alloc(4194304 * 2);
  short* VtB  = (short*)alloc(4194304 * 2);
  short* pre  = (short*)alloc(4194304 * 2);
  short* rlbf = (short*)alloc(65536 * 2);
  float* Thr  = (float*)alloc(65536 * 4);
  if (off > ws_size) return;

  k_convert<<<dim3(4096, 6), 256, 0, stream>>>(x, y, Wq, Wk, Wv, Wo,
                                               x16, y16, wq16, wk16, wv16, wohi);

  k_gemm_f16<2><<<512, 256, 0, stream>>>(x16, wq16, bq, Q16, 4096, 1024, 1024);
  k_gemm_f16<2><<<512, 256, 0, stream>>>(y16, wk16, bk, K16, 4096, 1024, 1024);
  k_gemm_f16<0><<<512, 256, 0, stream>>>(y16, wv16, bv, Vb, 4096, 1024, 1024);
  k_mu<<<256, 256, 0, stream>>>(K16, Q16, Thr);
  k_passA_fuse<<<1024, 256, 0, stream>>>(Q16, K16, Vb, VtB, rlbf);
  k_passB<<<512, 256, 0, stream>>>(Q16, K16, VtB, rlbf, Thr, pre, rm);
  k_gemm_out<<<512, 256, 0, stream>>>(pre, wohi, bo, out, 4096, 1024, 1024);
}

// Round 16
// 155.670 us; speedup vs baseline: 1.0052x; 1.0052x over previous
//
#include <hip/hip_runtime.h>
#include <hip/hip_bf16.h>
#include <stdint.h>

typedef float f32x4 __attribute__((ext_vector_type(4)));
typedef short bf16x8 __attribute__((ext_vector_type(8)));
typedef _Float16 f16x8 __attribute__((ext_vector_type(8)));

#define DEV static __device__ __forceinline__

DEV float bf2f(short u) {
  union { float f; unsigned i; } v;
  v.i = ((unsigned)(unsigned short)u) << 16;
  return v.f;
}
DEV short f2bf(float f) {
  union { float f; unsigned i; } v;
  v.f = f;
  unsigned lsb = (v.i >> 16) & 1u;
  v.i += 0x7fffu + lsb;
  return (short)(v.i >> 16);
}
DEV short f2h(float f) {
  union { _Float16 h; short s; } u;
  u.h = (_Float16)f;
  return u.s;
}

DEV void glds16(const void* g, void* l) {
  __builtin_amdgcn_global_load_lds(
      (const __attribute__((address_space(1))) void*)g,
      (__attribute__((address_space(3))) void*)l, 16, 0, 0);
}

// ---------------------------------------------------------------------------
// Convert fp32 -> fp16 (x, y, Wq, Wk, Wv) and bf16 (Wo)
// ---------------------------------------------------------------------------
__global__ __launch_bounds__(256) void k_convert(
    const float* __restrict__ x, const float* __restrict__ y,
    const float* __restrict__ wq, const float* __restrict__ wk,
    const float* __restrict__ wv, const float* __restrict__ wo,
    short* __restrict__ x16, short* __restrict__ y16,
    short* __restrict__ wq16, short* __restrict__ wk16,
    short* __restrict__ wv16, short* __restrict__ wohi) {
  const float* src; short* dst; int n, half;
  switch (blockIdx.y) {
    case 0: src = x;  dst = x16;  n = 4194304; half = 1; break;
    case 1: src = y;  dst = y16;  n = 4194304; half = 1; break;
    case 2: src = wq; dst = wq16; n = 1048576; half = 1; break;
    case 3: src = wk; dst = wk16; n = 1048576; half = 1; break;
    case 4: src = wv; dst = wv16; n = 1048576; half = 1; break;
    default: src = wo; dst = wohi; n = 1048576; half = 0; break;
  }
  int i4 = blockIdx.x * 256 + threadIdx.x;
  if (i4 * 4 >= n) return;
  float4 v = ((const float4*)src)[i4];
  short4 h;
  float* pv = (float*)&v;
  short* ph = (short*)&h;
#pragma unroll
  for (int e = 0; e < 4; ++e) ph[e] = half ? f2h(pv[e]) : f2bf(pv[e]);
  ((short4*)dst)[i4] = h;
}

// ---------------------------------------------------------------------------
// XCD-pinned block remap for 128x64 tiles: M=4096(32 row-panels) x
// N=1024(16 col-blocks). wg = rhigh*128 + c*8 + rlow (bijective, 512 blocks).
// ---------------------------------------------------------------------------
DEV void gemm_block_map64(int wg, long& bRow, long& bCol) {
  int rlow = wg & 7, c = (wg >> 3) & 15, rhigh = wg >> 7;
  bRow = (long)(rhigh * 8 + rlow) * 128;
  bCol = (long)c * 64;
}

// ---------------------------------------------------------------------------
// Plain bf16 NT GEMM with bias (Wo output projection). 128x64 tile,
// 4 waves (256 thr), double-buffered, 512 blocks = 2 blocks/CU.
// ---------------------------------------------------------------------------
__global__ __launch_bounds__(256) void k_gemm_out(
    const short* __restrict__ A, const short* __restrict__ B,
    const float* __restrict__ bias, float* __restrict__ C, int M, int N, int K) {
  __shared__ __align__(16) short As[2][128 * 64];
  __shared__ __align__(16) short Bs[2][64 * 64];
  const int tid = threadIdx.x, lane = tid & 63;
  const int w = tid >> 6;
  const int lo = lane & 15, hi4 = lane >> 4;
  long bRow, bCol;
  gemm_block_map64(blockIdx.x, bRow, bCol);
  f32x4 acc[2][4] = {};
  const int nks = K >> 6;
  auto stage = [&](int buf, int ks) {
#pragma unroll
    for (int i = 0; i < 4; ++i) {
      int c = i * 256 + tid;
      int r = c >> 3;
      int wi = ((c & 7) * 16) ^ ((r & 7) << 4);
      glds16((const char*)A + (bRow + r) * (long)(K * 2) + ks * 128 + wi, (char*)As[buf] + c * 16);
    }
#pragma unroll
    for (int i = 0; i < 2; ++i) {
      int c = i * 256 + tid;
      int r = c >> 3;
      int wi = ((c & 7) * 16) ^ ((r & 7) << 4);
      glds16((const char*)B + (bCol + r) * (long)(K * 2) + ks * 128 + wi, (char*)Bs[buf] + c * 16);
    }
  };
  stage(0, 0);
  __syncthreads();
  int p = 0;
  for (int ks = 0; ks < nks; ++ks) {
    if (ks + 1 < nks) stage(p ^ 1, ks + 1);
#pragma unroll
    for (int kk = 0; kk < 2; ++kk) {
      bf16x8 af[2], bfr[4];
#pragma unroll
      for (int m = 0; m < 2; ++m) {
        int r = w * 32 + m * 16 + lo;
        af[m] = *(const bf16x8*)((const char*)As[p] + r * 128 + ((kk * 64 + hi4 * 16) ^ ((r & 7) << 4)));
      }
#pragma unroll
      for (int n = 0; n < 4; ++n) {
        int r = n * 16 + lo;
        bfr[n] = *(const bf16x8*)((const char*)Bs[p] + r * 128 + ((kk * 64 + hi4 * 16) ^ ((r & 7) << 4)));
      }
#pragma unroll
      for (int m = 0; m < 2; ++m)
#pragma unroll
        for (int n = 0; n < 4; ++n)
          acc[m][n] = __builtin_amdgcn_mfma_f32_16x16x32_bf16(af[m], bfr[n], acc[m][n], 0, 0, 0);
    }
    __syncthreads();
    p ^= 1;
  }
#pragma unroll
  for (int n = 0; n < 4; ++n) {
    long col = bCol + n * 16 + lo;
    float bv = bias[col];
#pragma unroll
    for (int m = 0; m < 2; ++m) {
      long row0 = bRow + w * 32 + m * 16 + hi4 * 4;
#pragma unroll
      for (int j = 0; j < 4; ++j)
        C[(row0 + j) * N + col] = acc[m][n][j] + bv;
    }
  }
}

// ---------------------------------------------------------------------------
// fp16 NT GEMM with bias, 128x64 tile, 4 waves, double-buffered, 512 blocks.
// OUT_MODE=2: fp16 out. 0: bf16 out.
// ---------------------------------------------------------------------------
template <int OUT_MODE>
__global__ __launch_bounds__(256) void k_gemm_f16(
    const short* __restrict__ A, const short* __restrict__ B,
    const float* __restrict__ bias, short* __restrict__ C, int M, int N, int K) {
  __shared__ __align__(16) short As[2][128 * 64];
  __shared__ __align__(16) short Bs[2][64 * 64];
  const int tid = threadIdx.x, lane = tid & 63;
  const int w = tid >> 6;
  const int lo = lane & 15, hi4 = lane >> 4;
  long bRow, bCol;
  gemm_block_map64(blockIdx.x, bRow, bCol);
  f32x4 acc[2][4] = {};
  const int nks = K >> 6;
  auto stage = [&](int buf, int ks) {
#pragma unroll
    for (int i = 0; i < 4; ++i) {
      int c = i * 256 + tid;
      int r = c >> 3;
      int wi = ((c & 7) * 16) ^ ((r & 7) << 4);
      glds16((const char*)A + (bRow + r) * (long)(K * 2) + ks * 128 + wi, (char*)As[buf] + c * 16);
    }
#pragma unroll
    for (int i = 0; i < 2; ++i) {
      int c = i * 256 + tid;
      int r = c >> 3;
      int wi = ((c & 7) * 16) ^ ((r & 7) << 4);
      glds16((const char*)B + (bCol + r) * (long)(K * 2) + ks * 128 + wi, (char*)Bs[buf] + c * 16);
    }
  };
  stage(0, 0);
  __syncthreads();
  int p = 0;
  for (int ks = 0; ks < nks; ++ks) {
    if (ks + 1 < nks) stage(p ^ 1, ks + 1);
#pragma unroll
    for (int kk = 0; kk < 2; ++kk) {
      f16x8 af[2], bfr[4];
#pragma unroll
      for (int m = 0; m < 2; ++m) {
        int r = w * 32 + m * 16 + lo;
        af[m] = *(const f16x8*)((const char*)As[p] + r * 128 + ((kk * 64 + hi4 * 16) ^ ((r & 7) << 4)));
      }
#pragma unroll
      for (int n = 0; n < 4; ++n) {
        int r = n * 16 + lo;
        bfr[n] = *(const f16x8*)((const char*)Bs[p] + r * 128 + ((kk * 64 + hi4 * 16) ^ ((r & 7) << 4)));
      }
#pragma unroll
      for (int m = 0; m < 2; ++m)
#pragma unroll
        for (int n = 0; n < 4; ++n)
          acc[m][n] = __builtin_amdgcn_mfma_f32_16x16x32_f16(af[m], bfr[n], acc[m][n], 0, 0, 0);
    }
    __syncthreads();
    p ^= 1;
  }
#pragma unroll
  for (int n = 0; n < 4; ++n) {
    long col = bCol + n * 16 + lo;
    float bv = bias[col];
#pragma unroll
    for (int m = 0; m < 2; ++m)
#pragma unroll
      for (int j = 0; j < 4; ++j) {
        long row = bRow + w * 32 + m * 16 + hi4 * 4 + j;
        float v = acc[m][n][j] + bv;
        C[row * N + col] = (OUT_MODE == 2) ? f2h(v) : f2bf(v);
      }
  }
}

// ---------------------------------------------------------------------------
// k_mu: Thr[g,s] = (q_s . sum_t k_t) * NORM / 1024.  4 blocks per slice.
// ---------------------------------------------------------------------------
__global__ __launch_bounds__(256) void k_mu(
    const short* __restrict__ K16, const short* __restrict__ Q16,
    float* __restrict__ Thr) {
  __shared__ float tmp[32][64];
  __shared__ float ksum[64];
  const int g = blockIdx.x >> 2, q = blockIdx.x & 3;
  const int tid = threadIdx.x;
  const int d8 = tid & 7, tq = tid >> 3;
  const short* kp = K16 + (long)g * 65536;
  float acc[8] = {};
  for (int t = tq; t < 1024; t += 32) {
    f16x8 a = *(const f16x8*)(kp + t * 64 + d8 * 8);
#pragma unroll
    for (int e = 0; e < 8; ++e) acc[e] += (float)a[e];
  }
#pragma unroll
  for (int e = 0; e < 8; ++e) tmp[tq][d8 * 8 + e] = acc[e];
  __syncthreads();
  if (tid < 64) {
    float s = 0.f;
#pragma unroll
    for (int qq = 0; qq < 32; ++qq) s += tmp[qq][tid];
    ksum[tid] = s;
  }
  __syncthreads();
  const float c = 0.03125f / 1024.f;
  const int s = q * 256 + tid;
  const short* qp = Q16 + (long)g * 65536 + s * 64;
  float dot = 0.f;
#pragma unroll
  for (int d0 = 0; d0 < 64; d0 += 8) {
    f16x8 a = *(const f16x8*)(qp + d0);
#pragma unroll
    for (int e = 0; e < 8; ++e) dot += (float)a[e] * ksum[d0 + e];
  }
  Thr[g * 1024 + s] = dot * c;
}

// ---------------------------------------------------------------------------
// Pass A FUSED with V-scale/transpose (round-14 structure, setprio removed).
// ---------------------------------------------------------------------------
__global__ __launch_bounds__(256) void k_passA_fuse(
    const short* __restrict__ Q16, const short* __restrict__ K16,
    const short* __restrict__ Vb, short* __restrict__ Vt,
    short* __restrict__ rlbf) {
  __shared__ __align__(16) short Ks[64 * 64];
  __shared__ __align__(16) short Qs[2][64 * 64];
  __shared__ __align__(16) short T[64][80];
  __shared__ float rls[64];
  const int wg = blockIdx.x;
  const int g = (wg & 7) | ((wg >> 7) << 3);
  const int tb = (wg >> 3) & 15;
  const int tid = threadIdx.x, lane = tid & 63;
  const int w = tid >> 6;
  const int lo = lane & 15, hi4 = lane >> 4;
  const long gbase = (long)g * 131072;
  const float CEXP = 0.045136860026163146f;  // 2^-5 * log2(e)

  const short* vsrc = Vb + (long)g * 65536 + (long)tb * 64 * 64;
  bf16x8 vreg[2];
#pragma unroll
  for (int i = 0; i < 2; ++i) {
    int c = i * 256 + tid;
    vreg[i] = *(const bf16x8*)(vsrc + (c >> 3) * 64 + (c & 7) * 8);
  }

  auto stageQ = [&](int buf, int sb) {
#pragma unroll
    for (int i = 0; i < 2; ++i) {
      int c = i * 256 + tid;
      int r = c >> 3;
      int wi = ((c & 7) * 16) ^ ((r & 7) << 4);
      glds16((const char*)Q16 + gbase + (long)(sb * 64 + r) * 128 + wi, (char*)Qs[buf] + c * 16);
    }
  };
#pragma unroll
  for (int i = 0; i < 2; ++i) {
    int c = i * 256 + tid;
    int r = c >> 3;
    int wi = ((c & 7) * 16) ^ ((r & 7) << 4);
    glds16((const char*)K16 + gbase + (long)(tb * 64 + r) * 128 + wi, (char*)Ks + c * 16);
  }
  stageQ(0, 0);
  __syncthreads();
  f16x8 kf[2];
#pragma unroll
  for (int kk = 0; kk < 2; ++kk) {
    int r = w * 16 + lo;
    kf[kk] = *(const f16x8*)((const char*)Ks + r * 128 + ((kk * 64 + hi4 * 16) ^ ((r & 7) << 4)));
  }
  float Lacc[4] = {};
  int p = 0;
  for (int sb = 0; sb < 16; ++sb) {
    if (sb < 15) stageQ(p ^ 1, sb + 1);
    f32x4 s[4] = {};
#pragma unroll
    for (int kk = 0; kk < 2; ++kk) {
#pragma unroll
      for (int n = 0; n < 4; ++n) {
        int r = n * 16 + lo;
        f16x8 qf = *(const f16x8*)((const char*)Qs[p] + r * 128 +
                                   ((kk * 64 + hi4 * 16) ^ ((r & 7) << 4)));
        s[n] = __builtin_amdgcn_mfma_f32_16x16x32_f16(kf[kk], qf, s[n], 0, 0, 0);
      }
    }
#pragma unroll
    for (int n = 0; n < 4; ++n)
#pragma unroll
      for (int j = 0; j < 4; ++j)
        Lacc[j] += __builtin_amdgcn_exp2f(s[n][j] * CEXP);
    __syncthreads();
    p ^= 1;
  }
#pragma unroll
  for (int j = 0; j < 4; ++j) {
    float v = Lacc[j];
    v += __shfl_xor(v, 1);
    v += __shfl_xor(v, 2);
    v += __shfl_xor(v, 4);
    v += __shfl_xor(v, 8);
    if (lo == 0) {
      float rv = 1.0f / v;
      int idx = w * 16 + hi4 * 4 + j;
      rls[idx] = rv;
      rlbf[g * 1024 + tb * 64 + idx] = f2bf(rv);
    }
  }
  __syncthreads();
#pragma unroll
  for (int i = 0; i < 2; ++i) {
    int c = i * 256 + tid;
    int t = c >> 3, dc = (c & 7) * 8;
    float rv = rls[t];
#pragma unroll
    for (int e = 0; e < 8; ++e) T[dc + e][t] = f2bf(bf2f(vreg[i][e]) * rv);
  }
  __syncthreads();
  short* dst = Vt + (long)g * 65536 + tb * 64;
#pragma unroll
  for (int i = 0; i < 2; ++i) {
    int c = i * 256 + tid;
    int d = c >> 3, tc = (c & 7) * 8;
    bf16x8 o = *(const bf16x8*)(&T[d][tc]);
    *(bf16x8*)(dst + (long)d * 1024 + tc) = o;
  }
}

// ---------------------------------------------------------------------------
// Pass B: ROUND-14 proven structure (grid 1024, 40KB LDS, 16 waves/CU),
// setprio stripped (T5 is null-to-negative on lockstep barrier-synced
// structures, m190). Pipelined K/V dbuf, single P buffer, R/Z via 5th
// MFMA column on shared rl fragment. Numerics identical to rounds 13-15.
// ---------------------------------------------------------------------------
__global__ __launch_bounds__(256, 4) void k_passB(
    const short* __restrict__ Q16, const short* __restrict__ K16,
    const short* __restrict__ Vt, const short* __restrict__ rlbf,
    const float* __restrict__ Thr, short* __restrict__ Pre,
    const int* __restrict__ rmask) {
  __shared__ __align__(16) short Ks[2][64 * 64];
  __shared__ __align__(16) short Vs[2][64 * 64];
  __shared__ __align__(16) short Ps[64 * 64];
  const int wg = blockIdx.x;
  const int g = (wg & 7) | ((wg >> 7) << 3);
  const int rb = (wg >> 3) & 15;
  const int tid = threadIdx.x, lane = tid & 63;
  const int w = tid >> 6;
  const int lo = lane & 15, hi4 = lane >> 4;
  const long gbase = (long)g * 131072;
  const bool use_mask = (*rmask != 0);
  const int srow = w * 16 + lo;

  auto stage = [&](int buf, int tb2) {
#pragma unroll
    for (int i = 0; i < 2; ++i) {
      int c = i * 256 + tid;
      int r = c >> 3;
      int wi = ((c & 7) * 16) ^ ((r & 7) << 4);
      glds16((const char*)K16 + gbase + (long)(tb2 * 64 + r) * 128 + wi, (char*)Ks[buf] + c * 16);
      glds16((const char*)Vt + gbase + (long)r * 2048 + tb2 * 128 + wi, (char*)Vs[buf] + c * 16);
    }
  };

  f16x8 qf[2];
  {
    const char* qr = (const char*)Q16 + gbase + (long)(rb * 64 + srow) * 128;
#pragma unroll
    for (int kk = 0; kk < 2; ++kk)
      qf[kk] = *(const f16x8*)(qr + kk * 64 + hi4 * 16);
  }
  const float thre32 = use_mask ? Thr[g * 1024 + rb * 64 + srow] * 32.0f : -3.4e38f;
  const float CEXP = 0.045136860026163146f;  // 2^-5 * log2(e)
  f32x4 o1[4] = {}, o2[4] = {};
  f32x4 o1R = {}, o2Z = {};

  stage(0, 0);
  __syncthreads();
  int p = 0;
  for (int tb = 0; tb < 16; ++tb) {
    if (tb < 15) stage(p ^ 1, tb + 1);
    // --- S^T = K.Q^T (1-term fp16, 8 MFMA/wave) ---
    f32x4 s[4] = {};
#pragma unroll
    for (int kk = 0; kk < 2; ++kk) {
#pragma unroll
      for (int n = 0; n < 4; ++n) {
        int r = n * 16 + lo;
        f16x8 kf = *(const f16x8*)((const char*)Ks[p] + r * 128 +
                                   ((kk * 64 + hi4 * 16) ^ ((r & 7) << 4)));
        s[n] = __builtin_amdgcn_mfma_f32_16x16x32_f16(kf, qf[kk], s[n], 0, 0, 0);
      }
    }
    // --- softmax: P1 = e (store), P2 = masked e (keep words in regs) ---
    unsigned p2w0[4], p2w1[4];
#pragma unroll
    for (int n = 0; n < 4; ++n) {
      float ev[4], p2v[4];
#pragma unroll
      for (int j = 0; j < 4; ++j) {
        float sraw = s[n][j];
        float e = __builtin_amdgcn_exp2f(sraw * CEXP);
        ev[j] = e;
        p2v[j] = (sraw > thre32) ? e : 0.f;
      }
      unsigned u10, u11, u20, u21;
      asm("v_cvt_pk_bf16_f32 %0, %1, %2" : "=v"(u10) : "v"(ev[0]), "v"(ev[1]));
      asm("v_cvt_pk_bf16_f32 %0, %1, %2" : "=v"(u11) : "v"(ev[2]), "v"(ev[3]));
      asm("v_cvt_pk_bf16_f32 %0, %1, %2" : "=v"(u20) : "v"(p2v[0]), "v"(p2v[1]));
      asm("v_cvt_pk_bf16_f32 %0, %1, %2" : "=v"(u21) : "v"(p2v[2]), "v"(p2v[3]));
      p2w0[n] = u20;
      p2w1[n] = u21;
      int colb = n * 32 + hi4 * 8;
      int boff = srow * 128 + (colb ^ ((srow & 7) << 4));
      uint2 w1; w1.x = u10; w1.y = u11;
      *(uint2*)((char*)Ps + boff) = w1;
    }
    // --- PV pass 1 (P1 over pre-scaled V) + R = P1 . rl-frag ---
    bf16x8 vbreg[2][4], rlfr[2];
#pragma unroll
    for (int kk = 0; kk < 2; ++kk) {
      int poff = srow * 128 + ((kk * 64 + hi4 * 16) ^ ((srow & 7) << 4));
      bf16x8 pa1 = *(const bf16x8*)((const char*)Ps + poff);
      rlfr[kk] = *(const bf16x8*)(rlbf + g * 1024 + tb * 64 + kk * 32 + hi4 * 8);
      o1R = __builtin_amdgcn_mfma_f32_16x16x32_bf16(pa1, rlfr[kk], o1R, 0, 0, 0);
#pragma unroll
      for (int n = 0; n < 4; ++n) {
        int d = n * 16 + lo;
        vbreg[kk][n] = *(const bf16x8*)((const char*)Vs[p] + d * 128 +
                                        ((kk * 64 + hi4 * 16) ^ ((d & 7) << 4)));
        o1[n] = __builtin_amdgcn_mfma_f32_16x16x32_bf16(pa1, vbreg[kk][n], o1[n], 0, 0, 0);
      }
    }
    // --- store P2 over same buffer (wave-exclusive rows) ---
#pragma unroll
    for (int n = 0; n < 4; ++n) {
      int colb = n * 32 + hi4 * 8;
      int boff = srow * 128 + (colb ^ ((srow & 7) << 4));
      uint2 w2; w2.x = p2w0[n]; w2.y = p2w1[n];
      *(uint2*)((char*)Ps + boff) = w2;
    }
    // --- PV pass 2 (P2 over pre-scaled V) + Z = P2 . rl-frag ---
#pragma unroll
    for (int kk = 0; kk < 2; ++kk) {
      int poff = srow * 128 + ((kk * 64 + hi4 * 16) ^ ((srow & 7) << 4));
      bf16x8 pa2 = *(const bf16x8*)((const char*)Ps + poff);
      o2Z = __builtin_amdgcn_mfma_f32_16x16x32_bf16(pa2, rlfr[kk], o2Z, 0, 0, 0);
#pragma unroll
      for (int n = 0; n < 4; ++n)
        o2[n] = __builtin_amdgcn_mfma_f32_16x16x32_bf16(pa2, vbreg[kk][n], o2[n], 0, 0, 0);
    }
    __syncthreads();
    p ^= 1;
  }
  // --- epilogue: R/Z already per-thread in o1R/o2Z ---
#pragma unroll
  for (int j = 0; j < 4; ++j) {
    float rr = fmaxf(o1R[j], 1e-12f);
    float zz = fmaxf(o2Z[j], 1e-30f);
    float rinv = 0.5f / rr;
    float zinv = 0.5f / zz;
    int rl_ = w * 16 + hi4 * 4 + j;
#pragma unroll
    for (int n = 0; n < 4; ++n) {
      float val = o1[n][j] * rinv + o2[n][j] * zinv;
      Pre[(long)g * 65536 + (long)(rb * 64 + rl_) * 64 + n * 16 + lo] = f2bf(val);
    }
  }
}

// ---------------------------------------------------------------------------
extern "C" void kernel_launch(void* const* d_in, const int* in_sizes, int n_in,
                              void* d_out, int out_size, void* d_ws, size_t ws_size,
                              hipStream_t stream) {
  const float* x  = (const float*)d_in[0];
  const float* y  = (const float*)d_in[1];
  const float* Wq = (const float*)d_in[2];
  const float* bq = (const float*)d_in[3];
  const float* Wk = (const float*)d_in[4];
  const float* bk = (const float*)d_in[5];
  const float* Wv = (const float*)d_in[6];
  const float* bv = (const float*)d_in[7];
  const float* Wo = (const float*)d_in[8];
  const float* bo = (const float*)d_in[9];
  const int* rm   = (const int*)d_in[10];
  float* out = (float*)d_out;

  char* ws = (char*)d_ws;
  size_t off = 0;
  auto alloc = [&](size_t bytes) {
    char* p = ws + off;
    off += (bytes + 255) & ~(size_t)255;
    return p;
  };
  short* x16  = (short*)alloc(4194304 * 2);
  short* y16  = (short*)alloc(4194304 * 2);
  short* wq16 = (short*)alloc(1048576 * 2);
  short* wk16 = (short*)alloc(1048576 * 2);
  short* wv16 = (short*)alloc(1048576 * 2);
  short* wohi = (short*)alloc(1048576 * 2);
  short* Q16  = (short*)alloc(4194304 * 2);
  short* K16  = (short*)alloc(4194304 * 2);
  short* Vb   = (short*)alloc(4194304 * 2);
  short* VtB  = (short*)alloc(4194304 * 2);
  short* pre  = (short*)alloc(4194304 * 2);
  short* rlbf = (short*)alloc(65536 * 2);
  float* Thr  = (float*)alloc(65536 * 4);
  if (off > ws_size) return;

  k_convert<<<dim3(4096, 6), 256, 0, stream>>>(x, y, Wq, Wk, Wv, Wo,
                                               x16, y16, wq16, wk16, wv16, wohi);

  k_gemm_f16<2><<<512, 256, 0, stream>>>(x16, wq16, bq, Q16, 4096, 1024, 1024);
  k_gemm_f16<2><<<512, 256, 0, stream>>>(y16, wk16, bk, K16, 4096, 1024, 1024);
  k_gemm_f16<0><<<512, 256, 0, stream>>>(y16, wv16, bv, Vb, 4096, 1024, 1024);
  k_mu<<<256, 256, 0, stream>>>(K16, Q16, Thr);
  k_passA_fuse<<<1024, 256, 0, stream>>>(Q16, K16, Vb, VtB, rlbf);
  k_passB<<<1024, 256, 0, stream>>>(Q16, K16, VtB, rlbf, Thr, pre, rm);
  k_gemm_out<<<512, 256, 0, stream>>>(pre, wohi, bo, out, 4096, 1024, 1024);
}

// Round 17
// 138.277 us; speedup vs baseline: 1.1317x; 1.1258x over previous
//
#include <hip/hip_runtime.h>
#include <hip/hip_bf16.h>
#include <stdint.h>

typedef float f32x4 __attribute__((ext_vector_type(4)));
typedef short bf16x8 __attribute__((ext_vector_type(8)));
typedef _Float16 f16x8 __attribute__((ext_vector_type(8)));

#define DEV static __device__ __forceinline__

DEV float bf2f(short u) {
  union { float f; unsigned i; } v;
  v.i = ((unsigned)(unsigned short)u) << 16;
  return v.f;
}
DEV short f2bf(float f) {
  union { float f; unsigned i; } v;
  v.f = f;
  unsigned lsb = (v.i >> 16) & 1u;
  v.i += 0x7fffu + lsb;
  return (short)(v.i >> 16);
}
DEV short f2h(float f) {
  union { _Float16 h; short s; } u;
  u.h = (_Float16)f;
  return u.s;
}

DEV void glds16(const void* g, void* l) {
  __builtin_amdgcn_global_load_lds(
      (const __attribute__((address_space(1))) void*)g,
      (__attribute__((address_space(3))) void*)l, 16, 0, 0);
}

// ---------------------------------------------------------------------------
// Convert fp32 -> fp16 (x, y, Wq, Wk, Wv) and bf16 (Wo)
// ---------------------------------------------------------------------------
__global__ __launch_bounds__(256) void k_convert(
    const float* __restrict__ x, const float* __restrict__ y,
    const float* __restrict__ wq, const float* __restrict__ wk,
    const float* __restrict__ wv, const float* __restrict__ wo,
    short* __restrict__ x16, short* __restrict__ y16,
    short* __restrict__ wq16, short* __restrict__ wk16,
    short* __restrict__ wv16, short* __restrict__ wohi) {
  const float* src; short* dst; int n, half;
  switch (blockIdx.y) {
    case 0: src = x;  dst = x16;  n = 4194304; half = 1; break;
    case 1: src = y;  dst = y16;  n = 4194304; half = 1; break;
    case 2: src = wq; dst = wq16; n = 1048576; half = 1; break;
    case 3: src = wk; dst = wk16; n = 1048576; half = 1; break;
    case 4: src = wv; dst = wv16; n = 1048576; half = 1; break;
    default: src = wo; dst = wohi; n = 1048576; half = 0; break;
  }
  int i4 = blockIdx.x * 256 + threadIdx.x;
  if (i4 * 4 >= n) return;
  float4 v = ((const float4*)src)[i4];
  short4 h;
  float* pv = (float*)&v;
  short* ph = (short*)&h;
#pragma unroll
  for (int e = 0; e < 4; ++e) ph[e] = half ? f2h(pv[e]) : f2bf(pv[e]);
  ((short4*)dst)[i4] = h;
}

// ---------------------------------------------------------------------------
// XCD-pinned block remap for 128x64 tiles (512 blocks per GEMM instance).
// ---------------------------------------------------------------------------
DEV void gemm_block_map64(int wg, long& bRow, long& bCol) {
  int rlow = wg & 7, c = (wg >> 3) & 15, rhigh = wg >> 7;
  bRow = (long)(rhigh * 8 + rlow) * 128;
  bCol = (long)c * 64;
}

// ---------------------------------------------------------------------------
// Plain bf16 NT GEMM with bias (Wo output projection). 128x64 tile,
// 4 waves (256 thr), double-buffered, 512 blocks = 2 blocks/CU.
// ---------------------------------------------------------------------------
__global__ __launch_bounds__(256) void k_gemm_out(
    const short* __restrict__ A, const short* __restrict__ B,
    const float* __restrict__ bias, float* __restrict__ C, int M, int N, int K) {
  __shared__ __align__(16) short As[2][128 * 64];
  __shared__ __align__(16) short Bs[2][64 * 64];
  const int tid = threadIdx.x, lane = tid & 63;
  const int w = tid >> 6;
  const int lo = lane & 15, hi4 = lane >> 4;
  long bRow, bCol;
  gemm_block_map64(blockIdx.x, bRow, bCol);
  f32x4 acc[2][4] = {};
  const int nks = K >> 6;
  auto stage = [&](int buf, int ks) {
#pragma unroll
    for (int i = 0; i < 4; ++i) {
      int c = i * 256 + tid;
      int r = c >> 3;
      int wi = ((c & 7) * 16) ^ ((r & 7) << 4);
      glds16((const char*)A + (bRow + r) * (long)(K * 2) + ks * 128 + wi, (char*)As[buf] + c * 16);
    }
#pragma unroll
    for (int i = 0; i < 2; ++i) {
      int c = i * 256 + tid;
      int r = c >> 3;
      int wi = ((c & 7) * 16) ^ ((r & 7) << 4);
      glds16((const char*)B + (bCol + r) * (long)(K * 2) + ks * 128 + wi, (char*)Bs[buf] + c * 16);
    }
  };
  stage(0, 0);
  __syncthreads();
  int p = 0;
  for (int ks = 0; ks < nks; ++ks) {
    if (ks + 1 < nks) stage(p ^ 1, ks + 1);
#pragma unroll
    for (int kk = 0; kk < 2; ++kk) {
      bf16x8 af[2], bfr[4];
#pragma unroll
      for (int m = 0; m < 2; ++m) {
        int r = w * 32 + m * 16 + lo;
        af[m] = *(const bf16x8*)((const char*)As[p] + r * 128 + ((kk * 64 + hi4 * 16) ^ ((r & 7) << 4)));
      }
#pragma unroll
      for (int n = 0; n < 4; ++n) {
        int r = n * 16 + lo;
        bfr[n] = *(const bf16x8*)((const char*)Bs[p] + r * 128 + ((kk * 64 + hi4 * 16) ^ ((r & 7) << 4)));
      }
#pragma unroll
      for (int m = 0; m < 2; ++m)
#pragma unroll
        for (int n = 0; n < 4; ++n)
          acc[m][n] = __builtin_amdgcn_mfma_f32_16x16x32_bf16(af[m], bfr[n], acc[m][n], 0, 0, 0);
    }
    __syncthreads();
    p ^= 1;
  }
#pragma unroll
  for (int n = 0; n < 4; ++n) {
    long col = bCol + n * 16 + lo;
    float bv = bias[col];
#pragma unroll
    for (int m = 0; m < 2; ++m) {
      long row0 = bRow + w * 32 + m * 16 + hi4 * 4;
#pragma unroll
      for (int j = 0; j < 4; ++j)
        C[(row0 + j) * N + col] = acc[m][n][j] + bv;
    }
  }
}

// ---------------------------------------------------------------------------
// FUSED Q/K/V projection launch: 1536 blocks; blocks [0,512)=Q, [512,1024)=K,
// [1024,1536)=V. Bodies identical to round-16's k_gemm_f16; operand pointers
// selected per block (uniform branch). Q,K -> fp16 out; V -> bf16 out.
// ---------------------------------------------------------------------------
__global__ __launch_bounds__(256) void k_gemm_qkv(
    const short* __restrict__ x16, const short* __restrict__ y16,
    const short* __restrict__ wq16, const short* __restrict__ wk16,
    const short* __restrict__ wv16,
    const float* __restrict__ bq, const float* __restrict__ bk,
    const float* __restrict__ bv,
    short* __restrict__ Q16, short* __restrict__ K16, short* __restrict__ Vb) {
  __shared__ __align__(16) short As[2][128 * 64];
  __shared__ __align__(16) short Bs[2][64 * 64];
  const int which = blockIdx.x >> 9;   // 0=Q, 1=K, 2=V
  const int wg = blockIdx.x & 511;
  const short* A = (which == 0) ? x16 : y16;
  const short* B = (which == 0) ? wq16 : (which == 1) ? wk16 : wv16;
  const float* bias = (which == 0) ? bq : (which == 1) ? bk : bv;
  short* C = (which == 0) ? Q16 : (which == 1) ? K16 : Vb;
  const int out_h = (which != 2);
  const int tid = threadIdx.x, lane = tid & 63;
  const int w = tid >> 6;
  const int lo = lane & 15, hi4 = lane >> 4;
  long bRow, bCol;
  gemm_block_map64(wg, bRow, bCol);
  const int N = 1024, K = 1024;
  f32x4 acc[2][4] = {};
  const int nks = K >> 6;
  auto stage = [&](int buf, int ks) {
#pragma unroll
    for (int i = 0; i < 4; ++i) {
      int c = i * 256 + tid;
      int r = c >> 3;
      int wi = ((c & 7) * 16) ^ ((r & 7) << 4);
      glds16((const char*)A + (bRow + r) * (long)(K * 2) + ks * 128 + wi, (char*)As[buf] + c * 16);
    }
#pragma unroll
    for (int i = 0; i < 2; ++i) {
      int c = i * 256 + tid;
      int r = c >> 3;
      int wi = ((c & 7) * 16) ^ ((r & 7) << 4);
      glds16((const char*)B + (bCol + r) * (long)(K * 2) + ks * 128 + wi, (char*)Bs[buf] + c * 16);
    }
  };
  stage(0, 0);
  __syncthreads();
  int p = 0;
  for (int ks = 0; ks < nks; ++ks) {
    if (ks + 1 < nks) stage(p ^ 1, ks + 1);
#pragma unroll
    for (int kk = 0; kk < 2; ++kk) {
      f16x8 af[2], bfr[4];
#pragma unroll
      for (int m = 0; m < 2; ++m) {
        int r = w * 32 + m * 16 + lo;
        af[m] = *(const f16x8*)((const char*)As[p] + r * 128 + ((kk * 64 + hi4 * 16) ^ ((r & 7) << 4)));
      }
#pragma unroll
      for (int n = 0; n < 4; ++n) {
        int r = n * 16 + lo;
        bfr[n] = *(const f16x8*)((const char*)Bs[p] + r * 128 + ((kk * 64 + hi4 * 16) ^ ((r & 7) << 4)));
      }
#pragma unroll
      for (int m = 0; m < 2; ++m)
#pragma unroll
        for (int n = 0; n < 4; ++n)
          acc[m][n] = __builtin_amdgcn_mfma_f32_16x16x32_f16(af[m], bfr[n], acc[m][n], 0, 0, 0);
    }
    __syncthreads();
    p ^= 1;
  }
#pragma unroll
  for (int n = 0; n < 4; ++n) {
    long col = bCol + n * 16 + lo;
    float bv = bias[col];
#pragma unroll
    for (int m = 0; m < 2; ++m)
#pragma unroll
      for (int j = 0; j < 4; ++j) {
        long row = bRow + w * 32 + m * 16 + hi4 * 4 + j;
        float v = acc[m][n][j] + bv;
        C[row * N + col] = out_h ? f2h(v) : f2bf(v);
      }
  }
}

// ---------------------------------------------------------------------------
// FUSED k_mu + passA launch: 1280 blocks; [0,256)=k_mu, [256,1280)=passA_fuse.
// Bodies identical to round-16 versions.
// ---------------------------------------------------------------------------
__global__ __launch_bounds__(256) void k_mu_passA(
    const short* __restrict__ Q16, const short* __restrict__ K16,
    const short* __restrict__ Vb, short* __restrict__ Vt,
    short* __restrict__ rlbf, float* __restrict__ Thr) {
  __shared__ __align__(16) short Ks[64 * 64];
  __shared__ __align__(16) short Qs[2][64 * 64];
  __shared__ __align__(16) short T[64][80];
  __shared__ float rls[64];
  const int tid = threadIdx.x;
  const float CEXP = 0.045136860026163146f;  // 2^-5 * log2(e)

  if (blockIdx.x < 256) {
    // ----- k_mu: Thr[g,s] = (q_s . sum_t k_t) * NORM / 1024 -----
    float(*tmp)[64] = (float(*)[64])Ks;  // reuse LDS
    float* ksum = rls;
    const int g = blockIdx.x >> 2, q = blockIdx.x & 3;
    const int d8 = tid & 7, tq = tid >> 3;
    const short* kp = K16 + (long)g * 65536;
    float acc[8] = {};
    for (int t = tq; t < 1024; t += 32) {
      f16x8 a = *(const f16x8*)(kp + t * 64 + d8 * 8);
#pragma unroll
      for (int e = 0; e < 8; ++e) acc[e] += (float)a[e];
    }
#pragma unroll
    for (int e = 0; e < 8; ++e) tmp[tq][d8 * 8 + e] = acc[e];
    __syncthreads();
    if (tid < 64) {
      float s = 0.f;
#pragma unroll
      for (int qq = 0; qq < 32; ++qq) s += tmp[qq][tid];
      ksum[tid] = s;
    }
    __syncthreads();
    const float c = 0.03125f / 1024.f;
    const int s = q * 256 + tid;
    const short* qp = Q16 + (long)g * 65536 + s * 64;
    float dot = 0.f;
#pragma unroll
    for (int d0 = 0; d0 < 64; d0 += 8) {
      f16x8 a = *(const f16x8*)(qp + d0);
#pragma unroll
      for (int e = 0; e < 8; ++e) dot += (float)a[e] * ksum[d0 + e];
    }
    Thr[g * 1024 + s] = dot * c;
    return;
  }

  // ----- passA_fuse -----
  const int wg = blockIdx.x - 256;
  const int g = (wg & 7) | ((wg >> 7) << 3);
  const int tb = (wg >> 3) & 15;
  const int lane = tid & 63;
  const int w = tid >> 6;
  const int lo = lane & 15, hi4 = lane >> 4;
  const long gbase = (long)g * 131072;

  const short* vsrc = Vb + (long)g * 65536 + (long)tb * 64 * 64;
  bf16x8 vreg[2];
#pragma unroll
  for (int i = 0; i < 2; ++i) {
    int c = i * 256 + tid;
    vreg[i] = *(const bf16x8*)(vsrc + (c >> 3) * 64 + (c & 7) * 8);
  }

  auto stageQ = [&](int buf, int sb) {
#pragma unroll
    for (int i = 0; i < 2; ++i) {
      int c = i * 256 + tid;
      int r = c >> 3;
      int wi = ((c & 7) * 16) ^ ((r & 7) << 4);
      glds16((const char*)Q16 + gbase + (long)(sb * 64 + r) * 128 + wi, (char*)Qs[buf] + c * 16);
    }
  };
#pragma unroll
  for (int i = 0; i < 2; ++i) {
    int c = i * 256 + tid;
    int r = c >> 3;
    int wi = ((c & 7) * 16) ^ ((r & 7) << 4);
    glds16((const char*)K16 + gbase + (long)(tb * 64 + r) * 128 + wi, (char*)Ks + c * 16);
  }
  stageQ(0, 0);
  __syncthreads();
  f16x8 kf[2];
#pragma unroll
  for (int kk = 0; kk < 2; ++kk) {
    int r = w * 16 + lo;
    kf[kk] = *(const f16x8*)((const char*)Ks + r * 128 + ((kk * 64 + hi4 * 16) ^ ((r & 7) << 4)));
  }
  float Lacc[4] = {};
  int p = 0;
  for (int sb = 0; sb < 16; ++sb) {
    if (sb < 15) stageQ(p ^ 1, sb + 1);
    f32x4 s[4] = {};
#pragma unroll
    for (int kk = 0; kk < 2; ++kk) {
#pragma unroll
      for (int n = 0; n < 4; ++n) {
        int r = n * 16 + lo;
        f16x8 qf = *(const f16x8*)((const char*)Qs[p] + r * 128 +
                                   ((kk * 64 + hi4 * 16) ^ ((r & 7) << 4)));
        s[n] = __builtin_amdgcn_mfma_f32_16x16x32_f16(kf[kk], qf, s[n], 0, 0, 0);
      }
    }
#pragma unroll
    for (int n = 0; n < 4; ++n)
#pragma unroll
      for (int j = 0; j < 4; ++j)
        Lacc[j] += __builtin_amdgcn_exp2f(s[n][j] * CEXP);
    __syncthreads();
    p ^= 1;
  }
#pragma unroll
  for (int j = 0; j < 4; ++j) {
    float v = Lacc[j];
    v += __shfl_xor(v, 1);
    v += __shfl_xor(v, 2);
    v += __shfl_xor(v, 4);
    v += __shfl_xor(v, 8);
    if (lo == 0) {
      float rv = 1.0f / v;
      int idx = w * 16 + hi4 * 4 + j;
      rls[idx] = rv;
      rlbf[g * 1024 + tb * 64 + idx] = f2bf(rv);
    }
  }
  __syncthreads();
#pragma unroll
  for (int i = 0; i < 2; ++i) {
    int c = i * 256 + tid;
    int t = c >> 3, dc = (c & 7) * 8;
    float rv = rls[t];
#pragma unroll
    for (int e = 0; e < 8; ++e) T[dc + e][t] = f2bf(bf2f(vreg[i][e]) * rv);
  }
  __syncthreads();
  short* dst = Vt + (long)g * 65536 + tb * 64;
#pragma unroll
  for (int i = 0; i < 2; ++i) {
    int c = i * 256 + tid;
    int d = c >> 3, tc = (c & 7) * 8;
    bf16x8 o = *(const bf16x8*)(&T[d][tc]);
    *(bf16x8*)(dst + (long)d * 1024 + tc) = o;
  }
}

// ---------------------------------------------------------------------------
// Pass B: round-16 proven structure (grid 1024, 40KB LDS, 16 waves/CU,
// no setprio). Pipelined K/V dbuf, single P buffer, R/Z via 5th MFMA column.
// ---------------------------------------------------------------------------
__global__ __launch_bounds__(256, 4) void k_passB(
    const short* __restrict__ Q16, const short* __restrict__ K16,
    const short* __restrict__ Vt, const short* __restrict__ rlbf,
    const float* __restrict__ Thr, short* __restrict__ Pre,
    const int* __restrict__ rmask) {
  __shared__ __align__(16) short Ks[2][64 * 64];
  __shared__ __align__(16) short Vs[2][64 * 64];
  __shared__ __align__(16) short Ps[64 * 64];
  const int wg = blockIdx.x;
  const int g = (wg & 7) | ((wg >> 7) << 3);
  const int rb = (wg >> 3) & 15;
  const int tid = threadIdx.x, lane = tid & 63;
  const int w = tid >> 6;
  const int lo = lane & 15, hi4 = lane >> 4;
  const long gbase = (long)g * 131072;
  const bool use_mask = (*rmask != 0);
  const int srow = w * 16 + lo;

  auto stage = [&](int buf, int tb2) {
#pragma unroll
    for (int i = 0; i < 2; ++i) {
      int c = i * 256 + tid;
      int r = c >> 3;
      int wi = ((c & 7) * 16) ^ ((r & 7) << 4);
      glds16((const char*)K16 + gbase + (long)(tb2 * 64 + r) * 128 + wi, (char*)Ks[buf] + c * 16);
      glds16((const char*)Vt + gbase + (long)r * 2048 + tb2 * 128 + wi, (char*)Vs[buf] + c * 16);
    }
  };

  f16x8 qf[2];
  {
    const char* qr = (const char*)Q16 + gbase + (long)(rb * 64 + srow) * 128;
#pragma unroll
    for (int kk = 0; kk < 2; ++kk)
      qf[kk] = *(const f16x8*)(qr + kk * 64 + hi4 * 16);
  }
  const float thre32 = use_mask ? Thr[g * 1024 + rb * 64 + srow] * 32.0f : -3.4e38f;
  const float CEXP = 0.045136860026163146f;  // 2^-5 * log2(e)
  f32x4 o1[4] = {}, o2[4] = {};
  f32x4 o1R = {}, o2Z = {};

  stage(0, 0);
  __syncthreads();
  int p = 0;
  for (int tb = 0; tb < 16; ++tb) {
    if (tb < 15) stage(p ^ 1, tb + 1);
    // --- S^T = K.Q^T (1-term fp16, 8 MFMA/wave) ---
    f32x4 s[4] = {};
#pragma unroll
    for (int kk = 0; kk < 2; ++kk) {
#pragma unroll
      for (int n = 0; n < 4; ++n) {
        int r = n * 16 + lo;
        f16x8 kf = *(const f16x8*)((const char*)Ks[p] + r * 128 +
                                   ((kk * 64 + hi4 * 16) ^ ((r & 7) << 4)));
        s[n] = __builtin_amdgcn_mfma_f32_16x16x32_f16(kf, qf[kk], s[n], 0, 0, 0);
      }
    }
    // --- softmax: P1 = e (store), P2 = masked e (keep words in regs) ---
    unsigned p2w0[4], p2w1[4];
#pragma unroll
    for (int n = 0; n < 4; ++n) {
      float ev[4], p2v[4];
#pragma unroll
      for (int j = 0; j < 4; ++j) {
        float sraw = s[n][j];
        float e = __builtin_amdgcn_exp2f(sraw * CEXP);
        ev[j] = e;
        p2v[j] = (sraw > thre32) ? e : 0.f;
      }
      unsigned u10, u11, u20, u21;
      asm("v_cvt_pk_bf16_f32 %0, %1, %2" : "=v"(u10) : "v"(ev[0]), "v"(ev[1]));
      asm("v_cvt_pk_bf16_f32 %0, %1, %2" : "=v"(u11) : "v"(ev[2]), "v"(ev[3]));
      asm("v_cvt_pk_bf16_f32 %0, %1, %2" : "=v"(u20) : "v"(p2v[0]), "v"(p2v[1]));
      asm("v_cvt_pk_bf16_f32 %0, %1, %2" : "=v"(u21) : "v"(p2v[2]), "v"(p2v[3]));
      p2w0[n] = u20;
      p2w1[n] = u21;
      int colb = n * 32 + hi4 * 8;
      int boff = srow * 128 + (colb ^ ((srow & 7) << 4));
      uint2 w1; w1.x = u10; w1.y = u11;
      *(uint2*)((char*)Ps + boff) = w1;
    }
    // --- PV pass 1 (P1 over pre-scaled V) + R = P1 . rl-frag ---
    bf16x8 vbreg[2][4], rlfr[2];
#pragma unroll
    for (int kk = 0; kk < 2; ++kk) {
      int poff = srow * 128 + ((kk * 64 + hi4 * 16) ^ ((srow & 7) << 4));
      bf16x8 pa1 = *(const bf16x8*)((const char*)Ps + poff);
      rlfr[kk] = *(const bf16x8*)(rlbf + g * 1024 + tb * 64 + kk * 32 + hi4 * 8);
      o1R = __builtin_amdgcn_mfma_f32_16x16x32_bf16(pa1, rlfr[kk], o1R, 0, 0, 0);
#pragma unroll
      for (int n = 0; n < 4; ++n) {
        int d = n * 16 + lo;
        vbreg[kk][n] = *(const bf16x8*)((const char*)Vs[p] + d * 128 +
                                        ((kk * 64 + hi4 * 16) ^ ((d & 7) << 4)));
        o1[n] = __builtin_amdgcn_mfma_f32_16x16x32_bf16(pa1, vbreg[kk][n], o1[n], 0, 0, 0);
      }
    }
    // --- store P2 over same buffer (wave-exclusive rows) ---
#pragma unroll
    for (int n = 0; n < 4; ++n) {
      int colb = n * 32 + hi4 * 8;
      int boff = srow * 128 + (colb ^ ((srow & 7) << 4));
      uint2 w2; w2.x = p2w0[n]; w2.y = p2w1[n];
      *(uint2*)((char*)Ps + boff) = w2;
    }
    // --- PV pass 2 (P2 over pre-scaled V) + Z = P2 . rl-frag ---
#pragma unroll
    for (int kk = 0; kk < 2; ++kk) {
      int poff = srow * 128 + ((kk * 64 + hi4 * 16) ^ ((srow & 7) << 4));
      bf16x8 pa2 = *(const bf16x8*)((const char*)Ps + poff);
      o2Z = __builtin_amdgcn_mfma_f32_16x16x32_bf16(pa2, rlfr[kk], o2Z, 0, 0, 0);
#pragma unroll
      for (int n = 0; n < 4; ++n)
        o2[n] = __builtin_amdgcn_mfma_f32_16x16x32_bf16(pa2, vbreg[kk][n], o2[n], 0, 0, 0);
    }
    __syncthreads();
    p ^= 1;
  }
  // --- epilogue: R/Z already per-thread in o1R/o2Z ---
#pragma unroll
  for (int j = 0; j < 4; ++j) {
    float rr = fmaxf(o1R[j], 1e-12f);
    float zz = fmaxf(o2Z[j], 1e-30f);
    float rinv = 0.5f / rr;
    float zinv = 0.5f / zz;
    int rl_ = w * 16 + hi4 * 4 + j;
#pragma unroll
    for (int n = 0; n < 4; ++n) {
      float val = o1[n][j] * rinv + o2[n][j] * zinv;
      Pre[(long)g * 65536 + (long)(rb * 64 + rl_) * 64 + n * 16 + lo] = f2bf(val);
    }
  }
}

// ---------------------------------------------------------------------------
extern "C" void kernel_launch(void* const* d_in, const int* in_sizes, int n_in,
                              void* d_out, int out_size, void* d_ws, size_t ws_size,
                              hipStream_t stream) {
  const float* x  = (const float*)d_in[0];
  const float* y  = (const float*)d_in[1];
  const float* Wq = (const float*)d_in[2];
  const float* bq = (const float*)d_in[3];
  const float* Wk = (const float*)d_in[4];
  const float* bk = (const float*)d_in[5];
  const float* Wv = (const float*)d_in[6];
  const float* bv = (const float*)d_in[7];
  const float* Wo = (const float*)d_in[8];
  const float* bo = (const float*)d_in[9];
  const int* rm   = (const int*)d_in[10];
  float* out = (float*)d_out;

  char* ws = (char*)d_ws;
  size_t off = 0;
  auto alloc = [&](size_t bytes) {
    char* p = ws + off;
    off += (bytes + 255) & ~(size_t)255;
    return p;
  };
  short* x16  = (short*)alloc(4194304 * 2);
  short* y16  = (short*)alloc(4194304 * 2);
  short* wq16 = (short*)alloc(1048576 * 2);
  short* wk16 = (short*)alloc(1048576 * 2);
  short* wv16 = (short*)alloc(1048576 * 2);
  short* wohi = (short*)alloc(1048576 * 2);
  short* Q16  = (short*)alloc(4194304 * 2);
  short* K16  = (short*)alloc(4194304 * 2);
  short* Vb   = (short*)alloc(4194304 * 2);
  short* VtB  = (short*)alloc(4194304 * 2);
  short* pre  = (short*)alloc(4194304 * 2);
  short* rlbf = (short*)alloc(65536 * 2);
  float* Thr  = (float*)alloc(65536 * 4);
  if (off > ws_size) return;

  k_convert<<<dim3(4096, 6), 256, 0, stream>>>(x, y, Wq, Wk, Wv, Wo,
                                               x16, y16, wq16, wk16, wv16, wohi);

  k_gemm_qkv<<<1536, 256, 0, stream>>>(x16, y16, wq16, wk16, wv16,
                                       bq, bk, bv, Q16, K16, Vb);
  k_mu_passA<<<1280, 256, 0, stream>>>(Q16, K16, Vb, VtB, rlbf, Thr);
  k_passB<<<1024, 256, 0, stream>>>(Q16, K16, VtB, rlbf, Thr, pre, rm);
  k_gemm_out<<<512, 256, 0, stream>>>(pre, wohi, bo, out, 4096, 1024, 1024);
}